// Round 2
// baseline (159.580 us; speedup 1.0000x reference)
//
#include <hip/hip_runtime.h>
#include <math.h>

// Problem constants
constexpr int EPG  = 512;     // edges per graph
constexpr int ETOT = 131072;  // total edges

// ws layout (float offsets) — only the layer-1 class tables live in ws now
constexpr size_t TAB_Q  = 0;
constexpr size_t TAB_K  = 1024;
constexpr size_t TAB_V  = 2048;
constexpr size_t TAB_S  = 3072;   // 4*64
constexpr size_t TAB_LG = 3328;   // 64

// ---------------------------------------------------------------------------
// Kernel A: time embedding + layer-1 class tables (x is one-hot(4), temb is
// node-constant => q1/k1/v1/skip1 take only 4 distinct rows; logits take 64
// distinct values lg[dst_class][src_class][head]).
// ---------------------------------------------------------------------------
__global__ __launch_bounds__(256) void k_tables(
    const int* __restrict__ t_ptr,
    const float* __restrict__ Wt,  const float* __restrict__ bt,
    const float* __restrict__ Wq1, const float* __restrict__ bq1,
    const float* __restrict__ Wk1, const float* __restrict__ bk1,
    const float* __restrict__ Wv1, const float* __restrict__ bv1,
    const float* __restrict__ Ws1, const float* __restrict__ bs1,
    float* __restrict__ ws)
{
    __shared__ float se[16], temb[16];
    __shared__ float q1t[4][256], k1t[4][256], v1t[4][256], s1t[4][64];
    const int t = threadIdx.x;

    if (t < 8) {
        float tv = (float)(*t_ptr) * 0.01f;        // t / T_STEPS
        float scale = logf(10000.0f) / 7.0f;       // half=8 -> /(half-1)
        float e = tv * expf(-(float)t * scale);
        se[t]     = sinf(e);
        se[t + 8] = cosf(e);
    }
    __syncthreads();
    if (t < 16) {
        float acc = bt[t];
        for (int i = 0; i < 16; i++) acc += se[i] * Wt[i * 16 + t];
        temb[t] = acc;
    }
    __syncthreads();
    {
        const int o = t;  // 0..255
        float tq = 0.f, tk = 0.f, tv = 0.f;
        for (int d = 0; d < 16; d++) {
            float td = temb[d];
            tq += td * Wq1[(4 + d) * 256 + o];
            tk += td * Wk1[(4 + d) * 256 + o];
            tv += td * Wv1[(4 + d) * 256 + o];
        }
        for (int c = 0; c < 4; c++) {
            q1t[c][o] = Wq1[c * 256 + o] + tq + bq1[o];
            k1t[c][o] = Wk1[c * 256 + o] + tk + bk1[o];
            v1t[c][o] = Wv1[c * 256 + o] + tv + bv1[o];
        }
        if (o < 64) {
            float ts = 0.f;
            for (int d = 0; d < 16; d++) ts += temb[d] * Ws1[(4 + d) * 64 + o];
            for (int c = 0; c < 4; c++) s1t[c][o] = Ws1[c * 64 + o] + ts + bs1[o];
        }
    }
    __syncthreads();
    for (int idx = t; idx < 1024; idx += 256) {
        int c = idx >> 8, o = idx & 255;
        ws[TAB_Q + idx] = q1t[c][o];
        ws[TAB_K + idx] = k1t[c][o];
        ws[TAB_V + idx] = v1t[c][o];
    }
    ws[TAB_S + t] = s1t[t >> 6][t & 63];
    if (t < 64) {
        int cd = t >> 4, cs = (t >> 2) & 3, h = t & 3;
        float acc = 0.f;
        for (int d = 0; d < 64; d++) acc += q1t[cd][h * 64 + d] * k1t[cs][h * 64 + d];
        ws[TAB_LG + t] = acc * 0.125f;   // / sqrt(64)
    }
}

// ---------------------------------------------------------------------------
// GEMV helpers: thread owns (row, 8 cols); A-row from LDS (b128 every 4 k),
// B rows 8-wide from global (L1/L2 broadcast across blocks) or LDS.
// ---------------------------------------------------------------------------
__device__ __forceinline__ void fma8(float a, const float* __restrict__ p,
                                     float* __restrict__ acc)
{
    float4 w0 = *(const float4*)p;
    float4 w1 = *(const float4*)(p + 4);
    acc[0] += a * w0.x; acc[1] += a * w0.y; acc[2] += a * w0.z; acc[3] += a * w0.w;
    acc[4] += a * w1.x; acc[5] += a * w1.y; acc[6] += a * w1.z; acc[7] += a * w1.w;
}

template <int LDW>
__device__ __forceinline__ void gemv8(const float* __restrict__ Arow,
                                      const float* __restrict__ W,   // + col offset
                                      float* __restrict__ acc)
{
    #pragma unroll 4
    for (int k = 0; k < 64; k += 4) {
        float4 a4 = *(const float4*)(Arow + k);
        fma8(a4.x, W + (size_t)(k + 0) * LDW, acc);
        fma8(a4.y, W + (size_t)(k + 1) * LDW, acc);
        fma8(a4.z, W + (size_t)(k + 2) * LDW, acc);
        fma8(a4.w, W + (size_t)(k + 3) * LDW, acc);
    }
}

// ---------------------------------------------------------------------------
// Mega-kernel: per-graph layer1 -> projections -> attention -> h2 ->
// node logits + edge-MLP factorization + edge logits. One block per graph,
// 512 threads (8 waves). All intermediates in LDS.
// Thread mapping for all GEMMs: row = t>>3 (0..63), cols d0..d0+7, d0=(t&7)*8.
// ---------------------------------------------------------------------------
__global__ __launch_bounds__(512) void k_main(
    const float* __restrict__ x, const int* __restrict__ ei,
    const float* __restrict__ ws,
    const float* __restrict__ Wq, const float* __restrict__ bq,
    const float* __restrict__ Wk, const float* __restrict__ bk,
    const float* __restrict__ Wv, const float* __restrict__ bv,
    const float* __restrict__ Wsk, const float* __restrict__ bsk,
    const float* __restrict__ Wn, const float* __restrict__ bn,
    const float* __restrict__ We1, const float* __restrict__ be1,
    const float* __restrict__ We2, const float* __restrict__ be2,
    float* __restrict__ out)
{
    __shared__ __align__(16) float hs[64 * 68];    // h1, later h2
    __shared__ __align__(16) float Qs[64 * 68];    // Q_head, later A
    __shared__ __align__(16) float KsT[64 * 68];   // K^T_head, later B^T
    __shared__ __align__(16) float Vs[64 * 68];    // V_head
    __shared__ __align__(16) float Ss[64 * 68];    // scores / P
    __shared__ int   Cc[2048];                     // ushort-packed counts [dst][src]
    __shared__ int   cnt4[64][4];                  // per-node incoming class histogram
    __shared__ int   cls[64];
    __shared__ float alpha[64][16];                // [node][h*4+c] incl 0.25 mean
    __shared__ float v1t[1024];
    __shared__ float s1t[256];
    __shared__ float lgs[64];
    __shared__ float w2s[128];                     // We2 as [2][64]
    __shared__ float WnS[256];

    const int g = blockIdx.x, t = threadIdx.x;
    const int row = t >> 3;        // 0..63
    const int sub = t & 7;
    const int d0  = sub * 8;

    // ---- P0: tables, class ids, zero counters -----------------------------
    for (int i = t; i < 1024; i += 512) v1t[i] = ws[TAB_V + i];
    if (t < 256) s1t[t] = ws[TAB_S + t];
    if (t < 64)  lgs[t] = ws[TAB_LG + t];
    if (t < 256) WnS[t] = Wn[t];
    if (t < 128) w2s[(t & 1) * 64 + (t >> 1)] = We2[t];
    if (t < 64) {
        const float* xr = x + (size_t)(g * 64 + t) * 4;
        cls[t] = (int)(xr[1] + 2.f * xr[2] + 3.f * xr[3] + 0.5f);
    }
    if (t < 256) cnt4[t >> 2][t & 3] = 0;
    for (int i = t; i < 2048; i += 512) Cc[i] = 0;
    __syncthreads();

    // ---- P1: edge counts ---------------------------------------------------
    {
        int ge = g * EPG + t;      // 512 threads == 512 edges per graph
        int ls = ei[ge] - g * 64;
        int ld = ei[ETOT + ge] - g * 64;
        int idx = ld * 64 + ls;
        atomicAdd(&Cc[idx >> 1], 1 << ((idx & 1) * 16));
        atomicAdd(&cnt4[ld][cls[ls]], 1);
    }
    __syncthreads();

    // ---- P2: layer-1 softmax over <=4 distinct logits ----------------------
    if (t < 256) {
        int n = t >> 2, h = t & 3;
        int cd = cls[n];
        int   c[4]; float l[4];
        #pragma unroll
        for (int cc = 0; cc < 4; cc++) {
            c[cc] = cnt4[n][cc];
            l[cc] = lgs[cd * 16 + cc * 4 + h];
        }
        float m = -1e30f;
        #pragma unroll
        for (int cc = 0; cc < 4; cc++) if (c[cc] > 0) m = fmaxf(m, l[cc]);
        float e[4]; float den = 0.f;
        #pragma unroll
        for (int cc = 0; cc < 4; cc++) {
            e[cc] = (c[cc] > 0) ? (float)c[cc] * expf(l[cc] - m) : 0.f;
            den += e[cc];
        }
        float inv = (den > 0.f) ? 0.25f / den : 0.f;
        #pragma unroll
        for (int cc = 0; cc < 4; cc++) alpha[n][h * 4 + cc] = e[cc] * inv;
    }
    __syncthreads();

    // ---- P3: h1 into LDS ----------------------------------------------------
    {
        int cd = cls[row];
        float a[16];
        #pragma unroll
        for (int q = 0; q < 16; q++) a[q] = alpha[row][q];
        float o[8];
        #pragma unroll
        for (int jj = 0; jj < 8; jj++) {
            int d = d0 + jj;
            float acc = s1t[cd * 64 + d];
            #pragma unroll
            for (int h = 0; h < 4; h++)
                #pragma unroll
                for (int c = 0; c < 4; c++)
                    acc += a[h * 4 + c] * v1t[c * 256 + h * 64 + d];
            o[jj] = fmaxf(acc, 0.f);
        }
        *(float4*)&hs[row * 68 + d0]     = make_float4(o[0], o[1], o[2], o[3]);
        *(float4*)&hs[row * 68 + d0 + 4] = make_float4(o[4], o[5], o[6], o[7]);
    }
    __syncthreads();

    const float* Arow = &hs[row * 68];

    // ---- P4: skip projection (kept in registers) ---------------------------
    float skp[8];
    {
        float4 b0 = *(const float4*)&bsk[d0];
        float4 b1 = *(const float4*)&bsk[d0 + 4];
        skp[0] = b0.x; skp[1] = b0.y; skp[2] = b0.z; skp[3] = b0.w;
        skp[4] = b1.x; skp[5] = b1.y; skp[6] = b1.z; skp[7] = b1.w;
        gemv8<64>(Arow, Wsk + d0, skp);
    }

    // ---- P5: 4 heads of attention ------------------------------------------
    float hacc[8] = {0, 0, 0, 0, 0, 0, 0, 0};
    for (int h = 0; h < 4; h++) {
        // Q projection (scaled by 1/8)
        {
            float qa[8] = {0, 0, 0, 0, 0, 0, 0, 0};
            gemv8<256>(Arow, Wq + h * 64 + d0, qa);
            float4 b0 = *(const float4*)&bq[h * 64 + d0];
            float4 b1 = *(const float4*)&bq[h * 64 + d0 + 4];
            *(float4*)&Qs[row * 68 + d0] = make_float4(
                (qa[0] + b0.x) * 0.125f, (qa[1] + b0.y) * 0.125f,
                (qa[2] + b0.z) * 0.125f, (qa[3] + b0.w) * 0.125f);
            *(float4*)&Qs[row * 68 + d0 + 4] = make_float4(
                (qa[4] + b1.x) * 0.125f, (qa[5] + b1.y) * 0.125f,
                (qa[6] + b1.z) * 0.125f, (qa[7] + b1.w) * 0.125f);
        }
        // K projection -> transposed store
        {
            float ka[8] = {0, 0, 0, 0, 0, 0, 0, 0};
            gemv8<256>(Arow, Wk + h * 64 + d0, ka);
            float4 b0 = *(const float4*)&bk[h * 64 + d0];
            float4 b1 = *(const float4*)&bk[h * 64 + d0 + 4];
            float kb[8] = {ka[0] + b0.x, ka[1] + b0.y, ka[2] + b0.z, ka[3] + b0.w,
                           ka[4] + b1.x, ka[5] + b1.y, ka[6] + b1.z, ka[7] + b1.w};
            #pragma unroll
            for (int jj = 0; jj < 8; jj++) KsT[(d0 + jj) * 68 + row] = kb[jj];
        }
        // V projection
        {
            float va[8] = {0, 0, 0, 0, 0, 0, 0, 0};
            gemv8<256>(Arow, Wv + h * 64 + d0, va);
            float4 b0 = *(const float4*)&bv[h * 64 + d0];
            float4 b1 = *(const float4*)&bv[h * 64 + d0 + 4];
            *(float4*)&Vs[row * 68 + d0] =
                make_float4(va[0] + b0.x, va[1] + b0.y, va[2] + b0.z, va[3] + b0.w);
            *(float4*)&Vs[row * 68 + d0 + 4] =
                make_float4(va[4] + b1.x, va[5] + b1.y, va[6] + b1.z, va[7] + b1.w);
        }
        __syncthreads();

        // S = Q K^T + softmax (with multi-edge counts)
        float inv;
        {
            float sa[8] = {0, 0, 0, 0, 0, 0, 0, 0};
            gemv8<68>(&Qs[row * 68], &KsT[d0], sa);
            int cv[8];
            #pragma unroll
            for (int jj = 0; jj < 8; jj++) {
                int idx = row * 64 + d0 + jj;
                cv[jj] = (Cc[idx >> 1] >> ((idx & 1) * 16)) & 0xffff;
            }
            float m = -1e30f;
            #pragma unroll
            for (int jj = 0; jj < 8; jj++) if (cv[jj] > 0) m = fmaxf(m, sa[jj]);
            m = fmaxf(m, __shfl_xor(m, 1, 8));
            m = fmaxf(m, __shfl_xor(m, 2, 8));
            m = fmaxf(m, __shfl_xor(m, 4, 8));
            float den = 0.f;
            float p[8];
            #pragma unroll
            for (int jj = 0; jj < 8; jj++) {
                p[jj] = (cv[jj] > 0) ? (float)cv[jj] * expf(sa[jj] - m) : 0.f;
                den += p[jj];
            }
            den += __shfl_xor(den, 1, 8);
            den += __shfl_xor(den, 2, 8);
            den += __shfl_xor(den, 4, 8);
            *(float4*)&Ss[row * 68 + d0]     = make_float4(p[0], p[1], p[2], p[3]);
            *(float4*)&Ss[row * 68 + d0 + 4] = make_float4(p[4], p[5], p[6], p[7]);
            inv = (den > 0.f) ? 1.f / den : 0.f;
        }
        __syncthreads();

        // PV
        {
            float pv[8] = {0, 0, 0, 0, 0, 0, 0, 0};
            gemv8<68>(&Ss[row * 68], &Vs[d0], pv);
            #pragma unroll
            for (int jj = 0; jj < 8; jj++) hacc[jj] += pv[jj] * inv;
        }
        __syncthreads();
    }

    // ---- P6: h2 = relu(mean_heads + skip) -> hs; node logits; A, B^T -------
    {
        float o[8];
        #pragma unroll
        for (int jj = 0; jj < 8; jj++) o[jj] = fmaxf(0.25f * hacc[jj] + skp[jj], 0.f);
        *(float4*)&hs[row * 68 + d0]     = make_float4(o[0], o[1], o[2], o[3]);
        *(float4*)&hs[row * 68 + d0 + 4] = make_float4(o[4], o[5], o[6], o[7]);
    }
    __syncthreads();
    {
        // A = h2 @ We1_top + be1 -> Qs (row-major); B = h2 @ We1_bot -> KsT (transposed)
        float aa[8] = {0, 0, 0, 0, 0, 0, 0, 0};
        float bb[8] = {0, 0, 0, 0, 0, 0, 0, 0};
        gemv8<64>(Arow, We1 + d0, aa);
        gemv8<64>(Arow, We1 + 64 * 64 + d0, bb);
        float4 b0 = *(const float4*)&be1[d0];
        float4 b1 = *(const float4*)&be1[d0 + 4];
        *(float4*)&Qs[row * 68 + d0] =
            make_float4(aa[0] + b0.x, aa[1] + b0.y, aa[2] + b0.z, aa[3] + b0.w);
        *(float4*)&Qs[row * 68 + d0 + 4] =
            make_float4(aa[4] + b1.x, aa[5] + b1.y, aa[6] + b1.z, aa[7] + b1.w);
        #pragma unroll
        for (int jj = 0; jj < 8; jj++) KsT[(d0 + jj) * 68 + row] = bb[jj];
    }
    if (t < 256) {   // node logits
        int n = t >> 2, c = t & 3;
        float acc = bn[c];
        #pragma unroll 4
        for (int k = 0; k < 64; k++) acc += hs[n * 68 + k] * WnS[k * 4 + c];
        out[(size_t)(g * 64 + n) * 4 + c] = acc;
    }
    __syncthreads();

    // ---- P7: edge logits: relu(A_i + B_j) @ We2 + be2 -----------------------
    {
        const int wv = t >> 6, j = t & 63;
        float e0[8], e1[8];
        const float cb0 = be2[0], cb1 = be2[1];
        #pragma unroll
        for (int ii = 0; ii < 8; ii++) { e0[ii] = cb0; e1[ii] = cb1; }
        for (int kb = 0; kb < 4; kb++) {
            const int k0 = kb * 16;
            float bj[16], wa[16], wb[16];
            #pragma unroll
            for (int q = 0; q < 16; q++) {
                bj[q] = KsT[(k0 + q) * 68 + j];   // B^T: per-k contiguous across lanes
                wa[q] = w2s[k0 + q];
                wb[q] = w2s[64 + k0 + q];
            }
            #pragma unroll
            for (int ii = 0; ii < 8; ii++) {
                const float* ar = &Qs[(wv * 8 + ii) * 68 + k0];
                #pragma unroll
                for (int q = 0; q < 16; q += 4) {
                    float4 a4 = *(const float4*)(ar + q);
                    float s;
                    s = fmaxf(a4.x + bj[q + 0], 0.f); e0[ii] += s * wa[q + 0]; e1[ii] += s * wb[q + 0];
                    s = fmaxf(a4.y + bj[q + 1], 0.f); e0[ii] += s * wa[q + 1]; e1[ii] += s * wb[q + 1];
                    s = fmaxf(a4.z + bj[q + 2], 0.f); e0[ii] += s * wa[q + 2]; e1[ii] += s * wb[q + 2];
                    s = fmaxf(a4.w + bj[q + 3], 0.f); e0[ii] += s * wa[q + 3]; e1[ii] += s * wb[q + 3];
                }
            }
        }
        float2* oe = (float2*)(out + 65536);
        #pragma unroll
        for (int ii = 0; ii < 8; ii++)
            oe[(size_t)(g * 64 + wv * 8 + ii) * 64 + j] = make_float2(e0[ii], e1[ii]);
    }
}

// ---------------------------------------------------------------------------
extern "C" void kernel_launch(void* const* d_in, const int* in_sizes, int n_in,
                              void* d_out, int out_size, void* d_ws, size_t ws_size,
                              hipStream_t stream)
{
    const float* x    = (const float*)d_in[0];
    const int*   ei   = (const int*)d_in[1];
    // d_in[2] = batch (unused; graphs are equal-sized & contiguous)
    const int*   tptr = (const int*)d_in[3];
    const float* Wt   = (const float*)d_in[4];
    const float* bt   = (const float*)d_in[5];
    const float* Wq1  = (const float*)d_in[6];
    const float* bq1  = (const float*)d_in[7];
    const float* Wk1  = (const float*)d_in[8];
    const float* bk1  = (const float*)d_in[9];
    const float* Wv1  = (const float*)d_in[10];
    const float* bv1  = (const float*)d_in[11];
    const float* Ws1  = (const float*)d_in[12];
    const float* bs1  = (const float*)d_in[13];
    const float* Wq2  = (const float*)d_in[14];
    const float* bq2  = (const float*)d_in[15];
    const float* Wk2  = (const float*)d_in[16];
    const float* bk2  = (const float*)d_in[17];
    const float* Wv2  = (const float*)d_in[18];
    const float* bv2  = (const float*)d_in[19];
    const float* Ws2  = (const float*)d_in[20];
    const float* bs2  = (const float*)d_in[21];
    const float* Wn   = (const float*)d_in[22];
    const float* bn   = (const float*)d_in[23];
    const float* We1  = (const float*)d_in[24];
    const float* be1  = (const float*)d_in[25];
    const float* We2  = (const float*)d_in[26];
    const float* be2  = (const float*)d_in[27];

    float* ws  = (float*)d_ws;
    float* out = (float*)d_out;

    k_tables<<<1, 256, 0, stream>>>(tptr, Wt, bt, Wq1, bq1, Wk1, bk1, Wv1, bv1, Ws1, bs1, ws);
    k_main<<<256, 512, 0, stream>>>(x, ei, ws,
                                    Wq2, bq2, Wk2, bk2, Wv2, bv2, Ws2, bs2,
                                    Wn, bn, We1, be1, We2, be2, out);
}

// Round 3
// 63.554 us; speedup vs baseline: 2.5109x; 2.5109x over previous
//
#include <hip/hip_runtime.h>
#include <math.h>

// Problem constants
constexpr int EPG  = 512;     // edges per graph
constexpr int ETOT = 131072;  // total edges

// ws float-region offsets (floats)
constexpr size_t TAB_Q  = 0;
constexpr size_t TAB_K  = 1024;
constexpr size_t TAB_V  = 2048;
constexpr size_t TAB_S  = 3072;   // 4*64
constexpr size_t TAB_LG = 3328;   // 64
// ws short-region offsets (shorts), region starts at (short*)(ws + 4096)
constexpr int PK_Q_HI   = 0;
constexpr int PK_Q_LO   = 16384;
constexpr int PK_K_HI   = 32768;
constexpr int PK_K_LO   = 49152;
constexpr int PK_V_HI   = 65536;
constexpr int PK_V_LO   = 81920;
constexpr int PK_S_HI   = 98304;
constexpr int PK_S_LO   = 102400;
constexpr int PK_E1T_HI = 106496;
constexpr int PK_E1T_LO = 110592;
constexpr int PK_E1B_HI = 114688;
constexpr int PK_E1B_LO = 118784;

typedef short bf16x8 __attribute__((ext_vector_type(8)));
typedef float f32x4  __attribute__((ext_vector_type(4)));

__device__ __forceinline__ short f2bf(float x) {
    unsigned u = __float_as_uint(x);
    u = (u + 0x7fffu + ((u >> 16) & 1u)) >> 16;   // RNE
    return (short)u;
}
__device__ __forceinline__ float bf2f(short h) {
    return __uint_as_float(((unsigned)(unsigned short)h) << 16);
}
__device__ __forceinline__ void splt(float x, short& hi, short& lo) {
    hi = f2bf(x);
    lo = f2bf(x - bf2f(hi));
}

// hi/lo split product: C += Ah*Bh + Ah*Bl + Al*Bh  (error ~2^-17 rel)
__device__ __forceinline__ f32x4 mfma3(bf16x8 ah, bf16x8 al, bf16x8 bh, bf16x8 bl, f32x4 c) {
    c = __builtin_amdgcn_mfma_f32_16x16x32_bf16(ah, bh, c, 0, 0, 0);
    c = __builtin_amdgcn_mfma_f32_16x16x32_bf16(ah, bl, c, 0, 0, 0);
    c = __builtin_amdgcn_mfma_f32_16x16x32_bf16(al, bh, c, 0, 0, 0);
    return c;
}

// A/B fragment from LDS row-major [64][72] bf16: lane holds row=base+(l&15),
// k = kb + (l>>4)*8 + e (m97-verified convention; both A and [N][K]-B reads).
__device__ __forceinline__ bf16x8 ldsfrag(const short* p, int rowb, int kb, int lane) {
    return *(const bf16x8*)&p[(rowb + (lane & 15)) * 72 + kb + ((lane >> 4) << 3)];
}
// B fragment from global pack [N][64] bf16
__device__ __forceinline__ bf16x8 gpfrag(const short* p, int colb, int kb, int lane) {
    return *(const bf16x8*)&p[((colb + (lane & 15)) << 6) + kb + ((lane >> 4) << 3)];
}

// ---------------------------------------------------------------------------
// Kernel A: time embedding + layer-1 class tables (unchanged).
// ---------------------------------------------------------------------------
__global__ __launch_bounds__(256) void k_tables(
    const int* __restrict__ t_ptr,
    const float* __restrict__ Wt,  const float* __restrict__ bt,
    const float* __restrict__ Wq1, const float* __restrict__ bq1,
    const float* __restrict__ Wk1, const float* __restrict__ bk1,
    const float* __restrict__ Wv1, const float* __restrict__ bv1,
    const float* __restrict__ Ws1, const float* __restrict__ bs1,
    float* __restrict__ ws)
{
    __shared__ float se[16], temb[16];
    __shared__ float q1t[4][256], k1t[4][256], v1t[4][256], s1t[4][64];
    const int t = threadIdx.x;

    if (t < 8) {
        float tv = (float)(*t_ptr) * 0.01f;
        float scale = logf(10000.0f) / 7.0f;
        float e = tv * expf(-(float)t * scale);
        se[t]     = sinf(e);
        se[t + 8] = cosf(e);
    }
    __syncthreads();
    if (t < 16) {
        float acc = bt[t];
        for (int i = 0; i < 16; i++) acc += se[i] * Wt[i * 16 + t];
        temb[t] = acc;
    }
    __syncthreads();
    {
        const int o = t;
        float tq = 0.f, tk = 0.f, tv = 0.f;
        for (int d = 0; d < 16; d++) {
            float td = temb[d];
            tq += td * Wq1[(4 + d) * 256 + o];
            tk += td * Wk1[(4 + d) * 256 + o];
            tv += td * Wv1[(4 + d) * 256 + o];
        }
        for (int c = 0; c < 4; c++) {
            q1t[c][o] = Wq1[c * 256 + o] + tq + bq1[o];
            k1t[c][o] = Wk1[c * 256 + o] + tk + bk1[o];
            v1t[c][o] = Wv1[c * 256 + o] + tv + bv1[o];
        }
        if (o < 64) {
            float ts = 0.f;
            for (int d = 0; d < 16; d++) ts += temb[d] * Ws1[(4 + d) * 64 + o];
            for (int c = 0; c < 4; c++) s1t[c][o] = Ws1[c * 64 + o] + ts + bs1[o];
        }
    }
    __syncthreads();
    for (int idx = t; idx < 1024; idx += 256) {
        int c = idx >> 8, o = idx & 255;
        ws[TAB_Q + idx] = q1t[c][o];
        ws[TAB_K + idx] = k1t[c][o];
        ws[TAB_V + idx] = v1t[c][o];
    }
    ws[TAB_S + t] = s1t[t >> 6][t & 63];
    if (t < 64) {
        int cd = t >> 4, cs = (t >> 2) & 3, h = t & 3;
        float acc = 0.f;
        for (int d = 0; d < 64; d++) acc += q1t[cd][h * 64 + d] * k1t[cs][h * 64 + d];
        ws[TAB_LG + t] = acc * 0.125f;
    }
}

// ---------------------------------------------------------------------------
// Kernel P: pack layer-2 weights transposed into bf16 hi/lo: pack[n][k].
// Wq/Wk/Wv: [64][256] -> [256][64]; Wsk,We1top,We1bot: [64][64] -> [64][64].
// ---------------------------------------------------------------------------
__global__ __launch_bounds__(256) void k_prep(
    const float* __restrict__ Wq, const float* __restrict__ Wk,
    const float* __restrict__ Wv, const float* __restrict__ Wsk,
    const float* __restrict__ We1, short* __restrict__ wsh)
{
    int b = blockIdx.x, t = threadIdx.x;
    const float* src; int N; int dhi; int nb;
    if (b < 64)       { src = Wq;           N = 256; dhi = PK_Q_HI;   nb = b; }
    else if (b < 128) { src = Wk;           N = 256; dhi = PK_K_HI;   nb = b - 64; }
    else if (b < 192) { src = Wv;           N = 256; dhi = PK_V_HI;   nb = b - 128; }
    else if (b < 208) { src = Wsk;          N = 64;  dhi = PK_S_HI;   nb = b - 192; }
    else if (b < 224) { src = We1;          N = 64;  dhi = PK_E1T_HI; nb = b - 208; }
    else              { src = We1 + 64*64;  N = 64;  dhi = PK_E1B_HI; nb = b - 224; }
    int dlo = dhi + N * 64;
    int n = nb * 4 + (t >> 6), kk = t & 63;
    float v = src[(size_t)kk * N + n];
    short hi, lo; splt(v, hi, lo);
    wsh[dhi + n * 64 + kk] = hi;
    wsh[dlo + n * 64 + kk] = lo;
}

// ---------------------------------------------------------------------------
// Mega-kernel: per-graph layer1 -> MFMA projections -> MFMA attention -> h2 ->
// node logits + MFMA edge factorization + fp32 edge MLP. 1 block/graph,
// 512 threads = 8 waves (4 row-bands x 2 col-halves).
// ---------------------------------------------------------------------------
__global__ __launch_bounds__(512) void k_main(
    const float* __restrict__ x, const int* __restrict__ ei,
    const float* __restrict__ ws, const short* __restrict__ wsh,
    const float* __restrict__ bq, const float* __restrict__ bk,
    const float* __restrict__ bv, const float* __restrict__ bsk,
    const float* __restrict__ Wn, const float* __restrict__ bn,
    const float* __restrict__ be1, const float* __restrict__ We2,
    const float* __restrict__ be2, float* __restrict__ out)
{
    __shared__ __align__(16) char smem[130304];
    short* hHi    = (short*)(smem + 0);        // [64][72] bf16
    short* hLo    = (short*)(smem + 9216);
    short* qHi    = (short*)(smem + 18432);
    short* qLo    = (short*)(smem + 27648);
    short* kHi    = (short*)(smem + 36864);
    short* kLo    = (short*)(smem + 46080);
    short* vtHi   = (short*)(smem + 55296);    // V transposed [dim][node]
    short* vtLo   = (short*)(smem + 64512);
    short* pHi    = (short*)(smem + 73728);
    short* pLo    = (short*)(smem + 82944);
    float* Ssf    = (float*)(smem + 92160);    // [64][68] f32 (S, later h2)
    int*   Cc     = (int*)(smem + 109568);     // 2048 ints
    int*   cnt4   = (int*)(smem + 117760);     // [64][4]
    float* alphaF = (float*)(smem + 118784);   // [64][16]
    float* v1t    = (float*)(smem + 122880);   // 1024
    float* s1t    = (float*)(smem + 126976);   // 256
    float* lgs    = (float*)(smem + 128000);   // 64
    float* WnS    = (float*)(smem + 128256);   // 256
    float* w2s    = (float*)(smem + 129280);   // 128
    float* invsf  = (float*)(smem + 129792);   // 64
    int*   cls    = (int*)(smem + 130048);     // 64
    float* Asf    = (float*)(smem + 18432);    // alias over q (after attn)
    float* BTf    = (float*)(smem + 36864);    // alias over k (after attn)

    const int g = blockIdx.x, t = threadIdx.x;
    const int lane = t & 63, w = t >> 6;
    const int rowb = (w & 3) * 16;     // 16-row band
    const int ch   = w >> 2;           // col half (0/1)
    const int row8 = t >> 3;           // softmax/h1 row mapping
    const int d08  = (t & 7) * 8;

    // ---- P0: tables + misc loads, zero counters ----------------------------
    for (int i = t; i < 1024; i += 512) v1t[i] = ws[TAB_V + i];
    if (t < 256) s1t[t] = ws[TAB_S + t];
    if (t < 64)  lgs[t] = ws[TAB_LG + t];
    if (t < 256) WnS[t] = Wn[t];
    if (t < 128) w2s[(t & 1) * 64 + (t >> 1)] = We2[t];
    if (t < 64) {
        const float* xr = x + (size_t)(g * 64 + t) * 4;
        int c = 0;
        if (xr[1] > 0.5f) c = 1;
        if (xr[2] > 0.5f) c = 2;
        if (xr[3] > 0.5f) c = 3;
        cls[t] = c;
    }
    if (t < 256) cnt4[t] = 0;
    for (int i = t; i < 2048; i += 512) Cc[i] = 0;
    __syncthreads();

    // ---- P1: edge counts ----------------------------------------------------
    {
        int ge = g * EPG + t;
        int ls = ei[ge] - g * 64;
        int ld = ei[ETOT + ge] - g * 64;
        int idx = ld * 64 + ls;
        atomicAdd(&Cc[idx >> 1], 1 << ((idx & 1) * 16));
        atomicAdd(&cnt4[ld * 4 + cls[ls]], 1);
    }
    __syncthreads();

    // ---- P2: layer-1 softmax over <=4 distinct logits -----------------------
    if (t < 256) {
        int n = t >> 2, h = t & 3;
        int cd = cls[n];
        int   c[4]; float l[4];
        #pragma unroll
        for (int cc = 0; cc < 4; cc++) {
            c[cc] = cnt4[n * 4 + cc];
            l[cc] = lgs[cd * 16 + cc * 4 + h];
        }
        float m = -1e30f;
        #pragma unroll
        for (int cc = 0; cc < 4; cc++) if (c[cc] > 0) m = fmaxf(m, l[cc]);
        float e[4]; float den = 0.f;
        #pragma unroll
        for (int cc = 0; cc < 4; cc++) {
            e[cc] = (c[cc] > 0) ? (float)c[cc] * expf(l[cc] - m) : 0.f;
            den += e[cc];
        }
        float inv = (den > 0.f) ? 0.25f / den : 0.f;
        #pragma unroll
        for (int cc = 0; cc < 4; cc++) alphaF[n * 16 + h * 4 + cc] = e[cc] * inv;
    }
    __syncthreads();

    // ---- P3: h1 -> bf16 hi/lo in LDS ---------------------------------------
    {
        int cd = cls[row8];
        float a[16];
        #pragma unroll
        for (int q = 0; q < 16; q++) a[q] = alphaF[row8 * 16 + q];
        #pragma unroll
        for (int jj = 0; jj < 8; jj++) {
            int d = d08 + jj;
            float acc = s1t[cd * 64 + d];
            #pragma unroll
            for (int h = 0; h < 4; h++)
                #pragma unroll
                for (int c = 0; c < 4; c++)
                    acc += a[h * 4 + c] * v1t[c * 256 + h * 64 + d];
            float o = fmaxf(acc, 0.f);
            short hi, lo; splt(o, hi, lo);
            hHi[row8 * 72 + d] = hi;
            hLo[row8 * 72 + d] = lo;
        }
    }
    __syncthreads();

    // ---- A-fragments of h1 (cached in regs for all projections) ------------
    bf16x8 Ah0 = ldsfrag(hHi, rowb, 0, lane),  Ah1 = ldsfrag(hHi, rowb, 32, lane);
    bf16x8 Al0 = ldsfrag(hLo, rowb, 0, lane),  Al1 = ldsfrag(hLo, rowb, 32, lane);

    // ---- P4: skip projection (kept in regs) --------------------------------
    f32x4 skacc[2];
    #pragma unroll
    for (int ct = 0; ct < 2; ct++) {
        int colb = ch * 32 + ct * 16;
        f32x4 a = {0.f, 0.f, 0.f, 0.f};
        a = mfma3(Ah0, Al0, gpfrag(wsh + PK_S_HI, colb, 0, lane),
                             gpfrag(wsh + PK_S_LO, colb, 0, lane), a);
        a = mfma3(Ah1, Al1, gpfrag(wsh + PK_S_HI, colb, 32, lane),
                             gpfrag(wsh + PK_S_LO, colb, 32, lane), a);
        float bb = bsk[colb + (lane & 15)];
        #pragma unroll
        for (int r = 0; r < 4; r++) a[r] += bb;
        skacc[ct] = a;
    }

    // ---- P5: 4 heads --------------------------------------------------------
    float hacc[2][4] = {};
    for (int h = 0; h < 4; h++) {
        // QKV projections for this head
        #pragma unroll
        for (int ct = 0; ct < 2; ct++) {
            int colb = ch * 32 + ct * 16;
            int gcol = h * 64 + colb;
            f32x4 qa = {0.f,0.f,0.f,0.f}, ka = {0.f,0.f,0.f,0.f}, va = {0.f,0.f,0.f,0.f};
            qa = mfma3(Ah0, Al0, gpfrag(wsh + PK_Q_HI, gcol, 0, lane),
                                  gpfrag(wsh + PK_Q_LO, gcol, 0, lane), qa);
            qa = mfma3(Ah1, Al1, gpfrag(wsh + PK_Q_HI, gcol, 32, lane),
                                  gpfrag(wsh + PK_Q_LO, gcol, 32, lane), qa);
            ka = mfma3(Ah0, Al0, gpfrag(wsh + PK_K_HI, gcol, 0, lane),
                                  gpfrag(wsh + PK_K_LO, gcol, 0, lane), ka);
            ka = mfma3(Ah1, Al1, gpfrag(wsh + PK_K_HI, gcol, 32, lane),
                                  gpfrag(wsh + PK_K_LO, gcol, 32, lane), ka);
            va = mfma3(Ah0, Al0, gpfrag(wsh + PK_V_HI, gcol, 0, lane),
                                  gpfrag(wsh + PK_V_LO, gcol, 0, lane), va);
            va = mfma3(Ah1, Al1, gpfrag(wsh + PK_V_HI, gcol, 32, lane),
                                  gpfrag(wsh + PK_V_LO, gcol, 32, lane), va);
            float bqv = bq[gcol + (lane & 15)];
            float bkv = bk[gcol + (lane & 15)];
            float bvv = bv[gcol + (lane & 15)];
            int cc = colb + (lane & 15);
            #pragma unroll
            for (int r = 0; r < 4; r++) {
                int rr = rowb + ((lane >> 4) << 2) + r;
                short hi, lo;
                splt((qa[r] + bqv) * 0.125f, hi, lo);
                qHi[rr * 72 + cc] = hi;  qLo[rr * 72 + cc] = lo;
                splt(ka[r] + bkv, hi, lo);
                kHi[rr * 72 + cc] = hi;  kLo[rr * 72 + cc] = lo;
                splt(va[r] + bvv, hi, lo);
                vtHi[cc * 72 + rr] = hi; vtLo[cc * 72 + rr] = lo;
            }
        }
        __syncthreads();

        // S = Q K^T (rows=query band, cols=j)
        {
            bf16x8 qh0 = ldsfrag(qHi, rowb, 0, lane),  qh1 = ldsfrag(qHi, rowb, 32, lane);
            bf16x8 ql0 = ldsfrag(qLo, rowb, 0, lane),  ql1 = ldsfrag(qLo, rowb, 32, lane);
            #pragma unroll
            for (int ct = 0; ct < 2; ct++) {
                int colb = ch * 32 + ct * 16;
                f32x4 s = {0.f, 0.f, 0.f, 0.f};
                s = mfma3(qh0, ql0, ldsfrag(kHi, colb, 0, lane),
                                     ldsfrag(kLo, colb, 0, lane), s);
                s = mfma3(qh1, ql1, ldsfrag(kHi, colb, 32, lane),
                                     ldsfrag(kLo, colb, 32, lane), s);
                int cc = colb + (lane & 15);
                #pragma unroll
                for (int r = 0; r < 4; r++)
                    Ssf[(rowb + ((lane >> 4) << 2) + r) * 68 + cc] = s[r];
            }
        }
        __syncthreads();

        // softmax with multi-edge counts -> P (bf16 hi/lo) + invs
        {
            int cv[8]; float sv[8];
            #pragma unroll
            for (int jj = 0; jj < 8; jj++) {
                int idx = row8 * 64 + d08 + jj;
                cv[jj] = (Cc[idx >> 1] >> ((idx & 1) * 16)) & 0xffff;
                sv[jj] = Ssf[row8 * 68 + d08 + jj];
            }
            float m = -1e30f;
            #pragma unroll
            for (int jj = 0; jj < 8; jj++) if (cv[jj] > 0) m = fmaxf(m, sv[jj]);
            m = fmaxf(m, __shfl_xor(m, 1, 8));
            m = fmaxf(m, __shfl_xor(m, 2, 8));
            m = fmaxf(m, __shfl_xor(m, 4, 8));
            float den = 0.f; float p[8];
            #pragma unroll
            for (int jj = 0; jj < 8; jj++) {
                p[jj] = (cv[jj] > 0) ? (float)cv[jj] * expf(sv[jj] - m) : 0.f;
                den += p[jj];
            }
            den += __shfl_xor(den, 1, 8);
            den += __shfl_xor(den, 2, 8);
            den += __shfl_xor(den, 4, 8);
            #pragma unroll
            for (int jj = 0; jj < 8; jj++) {
                short hi, lo; splt(p[jj], hi, lo);
                pHi[row8 * 72 + d08 + jj] = hi;
                pLo[row8 * 72 + d08 + jj] = lo;
            }
            if ((t & 7) == 0) invsf[row8] = (den > 0.f) ? 1.f / den : 0.f;
        }
        __syncthreads();

        // PV (B = V^T rows are dims -> contiguous j)
        {
            bf16x8 ph0 = ldsfrag(pHi, rowb, 0, lane),  ph1 = ldsfrag(pHi, rowb, 32, lane);
            bf16x8 pl0 = ldsfrag(pLo, rowb, 0, lane),  pl1 = ldsfrag(pLo, rowb, 32, lane);
            #pragma unroll
            for (int ct = 0; ct < 2; ct++) {
                int colb = ch * 32 + ct * 16;
                f32x4 pv = {0.f, 0.f, 0.f, 0.f};
                pv = mfma3(ph0, pl0, ldsfrag(vtHi, colb, 0, lane),
                                      ldsfrag(vtLo, colb, 0, lane), pv);
                pv = mfma3(ph1, pl1, ldsfrag(vtHi, colb, 32, lane),
                                      ldsfrag(vtLo, colb, 32, lane), pv);
                #pragma unroll
                for (int r = 0; r < 4; r++)
                    hacc[ct][r] += pv[r] * invsf[rowb + ((lane >> 4) << 2) + r];
            }
        }
        __syncthreads();
    }

    // ---- P6: h2 = relu(mean + skip) -> hHi/hLo (bf16) and Ssf (f32) --------
    #pragma unroll
    for (int ct = 0; ct < 2; ct++) {
        int colb = ch * 32 + ct * 16;
        int cc = colb + (lane & 15);
        #pragma unroll
        for (int r = 0; r < 4; r++) {
            int rr = rowb + ((lane >> 4) << 2) + r;
            float v = fmaxf(0.25f * hacc[ct][r] + skacc[ct][r], 0.f);
            short hi, lo; splt(v, hi, lo);
            hHi[rr * 72 + cc] = hi;
            hLo[rr * 72 + cc] = lo;
            Ssf[rr * 68 + cc] = v;
        }
    }
    __syncthreads();

    // ---- P7: A = h2@We1top + be1 (row-major), B^T = (h2@We1bot)^T ----------
    {
        bf16x8 ah0 = ldsfrag(hHi, rowb, 0, lane),  ah1 = ldsfrag(hHi, rowb, 32, lane);
        bf16x8 al0 = ldsfrag(hLo, rowb, 0, lane),  al1 = ldsfrag(hLo, rowb, 32, lane);
        #pragma unroll
        for (int ct = 0; ct < 2; ct++) {
            int colb = ch * 32 + ct * 16;
            f32x4 aa = {0.f,0.f,0.f,0.f}, bb2 = {0.f,0.f,0.f,0.f};
            aa  = mfma3(ah0, al0, gpfrag(wsh + PK_E1T_HI, colb, 0, lane),
                                   gpfrag(wsh + PK_E1T_LO, colb, 0, lane), aa);
            aa  = mfma3(ah1, al1, gpfrag(wsh + PK_E1T_HI, colb, 32, lane),
                                   gpfrag(wsh + PK_E1T_LO, colb, 32, lane), aa);
            bb2 = mfma3(ah0, al0, gpfrag(wsh + PK_E1B_HI, colb, 0, lane),
                                   gpfrag(wsh + PK_E1B_LO, colb, 0, lane), bb2);
            bb2 = mfma3(ah1, al1, gpfrag(wsh + PK_E1B_HI, colb, 32, lane),
                                   gpfrag(wsh + PK_E1B_LO, colb, 32, lane), bb2);
            float bev = be1[colb + (lane & 15)];
            int cc = colb + (lane & 15);
            #pragma unroll
            for (int r = 0; r < 4; r++) {
                int rr = rowb + ((lane >> 4) << 2) + r;
                Asf[rr * 68 + cc] = aa[r] + bev;
                BTf[cc * 68 + rr] = bb2[r];
            }
        }
    }
    // node logits (h2 f32 from Ssf)
    if (t < 256) {
        int n = t >> 2, c = t & 3;
        float acc = bn[c];
        #pragma unroll 4
        for (int k = 0; k < 64; k++) acc += Ssf[n * 68 + k] * WnS[k * 4 + c];
        out[(size_t)(g * 64 + n) * 4 + c] = acc;
    }
    __syncthreads();

    // ---- P8: edge logits: relu(A_i + B_j) @ We2 + be2 ----------------------
    {
        const int wv = t >> 6, j = t & 63;
        float e0[8], e1[8];
        const float cb0 = be2[0], cb1 = be2[1];
        #pragma unroll
        for (int ii = 0; ii < 8; ii++) { e0[ii] = cb0; e1[ii] = cb1; }
        for (int kb = 0; kb < 4; kb++) {
            const int k0 = kb * 16;
            float bj[16], wa[16], wb[16];
            #pragma unroll
            for (int q = 0; q < 16; q++) {
                bj[q] = BTf[(k0 + q) * 68 + j];
                wa[q] = w2s[k0 + q];
                wb[q] = w2s[64 + k0 + q];
            }
            #pragma unroll
            for (int ii = 0; ii < 8; ii++) {
                const float* ar = &Asf[(wv * 8 + ii) * 68 + k0];
                #pragma unroll
                for (int q = 0; q < 16; q += 4) {
                    float4 a4 = *(const float4*)(ar + q);
                    float s;
                    s = fmaxf(a4.x + bj[q + 0], 0.f); e0[ii] += s * wa[q + 0]; e1[ii] += s * wb[q + 0];
                    s = fmaxf(a4.y + bj[q + 1], 0.f); e0[ii] += s * wa[q + 1]; e1[ii] += s * wb[q + 1];
                    s = fmaxf(a4.z + bj[q + 2], 0.f); e0[ii] += s * wa[q + 2]; e1[ii] += s * wb[q + 2];
                    s = fmaxf(a4.w + bj[q + 3], 0.f); e0[ii] += s * wa[q + 3]; e1[ii] += s * wb[q + 3];
                }
            }
        }
        float2* oe = (float2*)(out + 65536);
        #pragma unroll
        for (int ii = 0; ii < 8; ii++)
            oe[(size_t)(g * 64 + wv * 8 + ii) * 64 + j] = make_float2(e0[ii], e1[ii]);
    }
}

// ---------------------------------------------------------------------------
extern "C" void kernel_launch(void* const* d_in, const int* in_sizes, int n_in,
                              void* d_out, int out_size, void* d_ws, size_t ws_size,
                              hipStream_t stream)
{
    const float* x    = (const float*)d_in[0];
    const int*   ei   = (const int*)d_in[1];
    const int*   tptr = (const int*)d_in[3];
    const float* Wt   = (const float*)d_in[4];
    const float* bt   = (const float*)d_in[5];
    const float* Wq1  = (const float*)d_in[6];
    const float* bq1  = (const float*)d_in[7];
    const float* Wk1  = (const float*)d_in[8];
    const float* bk1  = (const float*)d_in[9];
    const float* Wv1  = (const float*)d_in[10];
    const float* bv1  = (const float*)d_in[11];
    const float* Ws1  = (const float*)d_in[12];
    const float* bs1  = (const float*)d_in[13];
    const float* Wq2  = (const float*)d_in[14];
    const float* bq2  = (const float*)d_in[15];
    const float* Wk2  = (const float*)d_in[16];
    const float* bk2  = (const float*)d_in[17];
    const float* Wv2  = (const float*)d_in[18];
    const float* bv2  = (const float*)d_in[19];
    const float* Ws2  = (const float*)d_in[20];
    const float* bs2  = (const float*)d_in[21];
    const float* Wn   = (const float*)d_in[22];
    const float* bn   = (const float*)d_in[23];
    const float* We1  = (const float*)d_in[24];
    const float* be1  = (const float*)d_in[25];
    const float* We2  = (const float*)d_in[26];
    const float* be2  = (const float*)d_in[27];

    float* ws  = (float*)d_ws;
    short* wsh = (short*)(ws + 4096);
    float* out = (float*)d_out;

    k_tables<<<1, 256, 0, stream>>>(tptr, Wt, bt, Wq1, bq1, Wk1, bk1, Wv1, bv1, Ws1, bs1, ws);
    k_prep<<<240, 256, 0, stream>>>(Wq2, Wk2, Wv2, Ws2, We1, wsh);
    k_main<<<256, 512, 0, stream>>>(x, ei, ws, wsh,
                                    bq2, bk2, bv2, bs2, Wn, bn, be1, We2, be2, out);
}